// Round 4
// baseline (230.568 us; speedup 1.0000x reference)
//
#include <hip/hip_runtime.h>
#include <hip/hip_bf16.h>

#define T_TOKENS 16384
#define HIDDEN   2048
#define NEXP     64
#define TOPK     8
#define TOPKG    4
#define RSCALE   2.5f

#define TOKB     64                   // tokens per token-block (lane = token)
#define NTB      (T_TOKENS / TOKB)    // 256 token-blocks
#define NWAVE    8                    // wave w owns experts w*8..w*8+7
#define EPW      (NEXP / NWAVE)       // 8 experts per wave
#define KC       128                  // k-chunk (floats) staged per barrier
#define TSTR     132                  // token row stride in LDS (mod 32 == 4)
#define ESTR     68                   // logits row stride (mod 32 == 4)

// ---------------------------------------------------------------------------
// Shared per-token epilogue: lane = expert, scores one-per-lane.
// Matches jax tie-breaks (lower index wins on equal values).
// ---------------------------------------------------------------------------
__device__ __forceinline__ void token_epilogue(float logit, int lane, int token,
                                               float* __restrict__ out,
                                               float& psum, float& cnt)
{
    float s = 1.f / (1.f + expf(-logit));   // sigmoid, lane = expert

    // group max over 8 consecutive lanes
    float gm = s;
    gm = fmaxf(gm, __shfl_xor(gm, 1));
    gm = fmaxf(gm, __shfl_xor(gm, 2));
    gm = fmaxf(gm, __shfl_xor(gm, 4));

    // rank my group among the 8 group maxima (tie-break: lower index)
    const int myg = lane >> 3;
    int rank = 0;
    #pragma unroll
    for (int g = 0; g < 8; ++g) {
        float gs = __shfl(gm, g * 8);
        rank += (gs > gm) || (gs == gm && g < myg);
    }
    float routed = (rank < TOPKG) ? s : 0.f;

    // full-row score sum (aux normalization)
    float ssum = s;
    #pragma unroll
    for (int off = 1; off < 64; off <<= 1) ssum += __shfl_xor(ssum, off);
    psum += s / fmaxf(ssum, 1e-9f);

    // sequential top-8 wave argmax (value desc, lower index on ties)
    float v = routed;
    int   idx = lane;
    float denom = 0.f;
    float myv = 0.f;
    int   myi = 0;
    #pragma unroll
    for (int k = 0; k < TOPK; ++k) {
        float bv = v;
        int   bi = idx;
        #pragma unroll
        for (int off = 1; off < 64; off <<= 1) {
            float ov = __shfl_xor(bv, off);
            int   oi = __shfl_xor(bi, off);
            if (ov > bv || (ov == bv && oi < bi)) { bv = ov; bi = oi; }
        }
        denom += bv;
        if (lane == k) { myv = bv; myi = bi; }
        if (lane == bi) { v = -1.f; cnt += 1.f; }
    }
    float wscale = RSCALE / fmaxf(denom, 1e-9f);
    if (lane < TOPK) {
        out[(size_t)token * TOPK + lane] = (float)myi;
        out[(size_t)T_TOKENS * TOPK + (size_t)token * TOPK + lane] = myv * wscale;
    }
}

// ---------------------------------------------------------------------------
// Kernel 1 (fast path): K-split GEMM. grid = NTB * ksplit blocks.
// block (512 thr): lane = token, wave = 8-expert slice, K-range = klen floats.
// Writes 64x64 partial logits (coalesced via LDS transpose) to partial[].
// ---------------------------------------------------------------------------
__global__ __launch_bounds__(512)
void gemm_kernel(const float* __restrict__ tokens,
                 const float* __restrict__ W,
                 float* __restrict__ partial,
                 int ksplit, int klen)
{
    __shared__ float tokLds[TOKB * TSTR];   // 33 KB; reused for logits gather

    const int tid  = threadIdx.x;
    const int lane = tid & 63;
    const int wv   = __builtin_amdgcn_readfirstlane(tid >> 6);
    const int bid  = blockIdx.x;
    const int tb   = bid & (NTB - 1);
    const int ks   = bid >> 8;
    const int base = tb * TOKB;
    const int k0   = ks * klen;

    float acc[EPW];
    #pragma unroll
    for (int e = 0; e < EPW; ++e) acc[e] = 0.f;

    const float* Wv = W + (size_t)wv * EPW * HIDDEN + k0;
    const int nch = klen / KC;

    for (int c = 0; c < nch; ++c) {
        // stage 64 tokens x 128 floats: 2048 float4 over 512 threads
        #pragma unroll
        for (int it = 0; it < 4; ++it) {
            int i  = it * 512 + tid;
            int t  = i >> 5;
            int j4 = i & 31;
            *(float4*)&tokLds[t * TSTR + j4 * 4] =
                *(const float4*)&tokens[(size_t)(base + t) * HIDDEN + k0 + c * KC + j4 * 4];
        }
        __syncthreads();

        #pragma unroll 4
        for (int k4 = 0; k4 < KC / 4; ++k4) {
            float4 t4 = *(const float4*)&tokLds[lane * TSTR + k4 * 4];
            #pragma unroll
            for (int e = 0; e < EPW; ++e) {
                const float* wp = &Wv[(size_t)e * HIDDEN + c * KC + k4 * 4]; // uniform -> s_load
                acc[e] = fmaf(wp[0], t4.x, acc[e]);
                acc[e] = fmaf(wp[1], t4.y, acc[e]);
                acc[e] = fmaf(wp[2], t4.z, acc[e]);
                acc[e] = fmaf(wp[3], t4.w, acc[e]);
            }
        }
        __syncthreads();
    }

    // gather logits: row = token(lane), cols = this wave's 8 experts
    *(float4*)&tokLds[lane * ESTR + wv * EPW]     = make_float4(acc[0], acc[1], acc[2], acc[3]);
    *(float4*)&tokLds[lane * ESTR + wv * EPW + 4] = make_float4(acc[4], acc[5], acc[6], acc[7]);
    __syncthreads();

    // coalesced partial write: 64 tokens x 64 experts = 1024 float4
    #pragma unroll
    for (int it = 0; it < 2; ++it) {
        int i  = it * 512 + tid;
        int t  = i >> 4;
        int e4 = i & 15;
        float4 v = *(const float4*)&tokLds[t * ESTR + e4 * 4];
        *(float4*)&partial[((size_t)ks * T_TOKENS + base + t) * NEXP + e4 * 4] = v;
    }
}

// ---------------------------------------------------------------------------
// Kernel 2 (fast path): sum ksplit partials (fixed order) + epilogue.
// grid = 256 blocks x 256 threads; wave handles 16 tokens.
// ---------------------------------------------------------------------------
__global__ __launch_bounds__(256)
void epilogue_kernel(const float* __restrict__ partial,
                     float* __restrict__ out,
                     float* __restrict__ wsP,
                     float* __restrict__ wsC,
                     int ksplit)
{
    __shared__ float redP[4][NEXP];
    __shared__ float redC[4][NEXP];

    const int tid  = threadIdx.x;
    const int lane = tid & 63;
    const int wv   = tid >> 6;                 // 0..3
    const int base = blockIdx.x * 64 + wv * 16;

    float psum = 0.f, cnt = 0.f;

    for (int tt = 0; tt < 16; ++tt) {
        const int token = base + tt;
        float logit = 0.f;
        for (int ks = 0; ks < ksplit; ++ks)    // fixed order -> deterministic
            logit += partial[((size_t)ks * T_TOKENS + token) * NEXP + lane];
        token_epilogue(logit, lane, token, out, psum, cnt);
    }

    redP[wv][lane] = psum;
    redC[wv][lane] = cnt;
    __syncthreads();
    if (tid < 64) {
        float p = redP[0][tid] + redP[1][tid] + redP[2][tid] + redP[3][tid];
        float c = redC[0][tid] + redC[1][tid] + redC[2][tid] + redC[3][tid];
        wsP[(size_t)blockIdx.x * 64 + tid] = p;
        wsC[(size_t)blockIdx.x * 64 + tid] = c;
    }
}

// ---------------------------------------------------------------------------
// Fallback fused kernel (round-3, known-good) for tiny workspaces.
// ---------------------------------------------------------------------------
__global__ __launch_bounds__(512)
void router_fused(const float* __restrict__ tokens,
                  const float* __restrict__ W,
                  float* __restrict__ out,
                  float* __restrict__ wsP,
                  float* __restrict__ wsC,
                  int atomicMode)
{
    __shared__ float tokLds[TOKB * TSTR];
    __shared__ float redP[NWAVE][NEXP];
    __shared__ float redC[NWAVE][NEXP];

    const int tid  = threadIdx.x;
    const int lane = tid & 63;
    const int wv   = __builtin_amdgcn_readfirstlane(tid >> 6);
    const int base = blockIdx.x * TOKB;

    float acc[EPW];
    #pragma unroll
    for (int e = 0; e < EPW; ++e) acc[e] = 0.f;

    const float* Wv = W + (size_t)wv * EPW * HIDDEN;

    for (int c = 0; c < HIDDEN / KC; ++c) {
        #pragma unroll
        for (int it = 0; it < 4; ++it) {
            int i  = it * 512 + tid;
            int t  = i >> 5;
            int j4 = i & 31;
            *(float4*)&tokLds[t * TSTR + j4 * 4] =
                *(const float4*)&tokens[(size_t)(base + t) * HIDDEN + c * KC + j4 * 4];
        }
        __syncthreads();
        #pragma unroll 2
        for (int k4 = 0; k4 < KC / 4; ++k4) {
            float4 t4 = *(const float4*)&tokLds[lane * TSTR + k4 * 4];
            #pragma unroll
            for (int e = 0; e < EPW; ++e) {
                const float* wp = &Wv[(size_t)e * HIDDEN + c * KC + k4 * 4];
                acc[e] = fmaf(wp[0], t4.x, acc[e]);
                acc[e] = fmaf(wp[1], t4.y, acc[e]);
                acc[e] = fmaf(wp[2], t4.z, acc[e]);
                acc[e] = fmaf(wp[3], t4.w, acc[e]);
            }
        }
        __syncthreads();
    }

    *(float4*)&tokLds[lane * ESTR + wv * EPW]     = make_float4(acc[0], acc[1], acc[2], acc[3]);
    *(float4*)&tokLds[lane * ESTR + wv * EPW + 4] = make_float4(acc[4], acc[5], acc[6], acc[7]);
    __syncthreads();

    float psum = 0.f, cnt = 0.f;
    #pragma unroll
    for (int tt = 0; tt < 8; ++tt) {
        const int tloc = wv * 8 + tt;
        token_epilogue(tokLds[tloc * ESTR + lane], lane, base + tloc, out, psum, cnt);
    }

    redP[wv][lane] = psum;
    redC[wv][lane] = cnt;
    __syncthreads();
    if (tid < 64) {
        float p = 0.f, c = 0.f;
        #pragma unroll
        for (int w = 0; w < NWAVE; ++w) { p += redP[w][tid]; c += redC[w][tid]; }
        if (atomicMode) { atomicAdd(&wsP[tid], p); atomicAdd(&wsC[tid], c); }
        else { wsP[(size_t)blockIdx.x * 64 + tid] = p; wsC[(size_t)blockIdx.x * 64 + tid] = c; }
    }
}

// ---------------------------------------------------------------------------
// Kernel 3: reduce per-block stats -> aux loss scalar at out[T*K*2]
// ---------------------------------------------------------------------------
__global__ __launch_bounds__(256)
void aux_kernel(const float* __restrict__ wsP,
                const float* __restrict__ wsC,
                float* __restrict__ out, int nblk)
{
    __shared__ float sP[256];
    __shared__ float sC[256];
    const int tid  = threadIdx.x;
    const int e    = tid & 63;
    const int part = tid >> 6;
    float p = 0.f, c = 0.f;
    for (int b = part; b < nblk; b += 4) {
        p += wsP[(size_t)b * 64 + e];
        c += wsC[(size_t)b * 64 + e];
    }
    sP[tid] = p; sC[tid] = c;
    __syncthreads();
    if (tid < 64) {
        p = sP[tid] + sP[tid + 64] + sP[tid + 128] + sP[tid + 192];
        c = sC[tid] + sC[tid + 64] + sC[tid + 128] + sC[tid + 192];
        float val = (c * (1.f / ((float)T_TOKENS * (float)TOPK)))
                  * (p * (1.f / (float)T_TOKENS));
        #pragma unroll
        for (int off = 1; off < 64; off <<= 1) val += __shfl_xor(val, off);
        if (tid == 0) out[(size_t)T_TOKENS * TOPK * 2] = val * (float)NEXP;
    }
}

extern "C" void kernel_launch(void* const* d_in, const int* in_sizes, int n_in,
                              void* d_out, int out_size, void* d_ws, size_t ws_size,
                              hipStream_t stream)
{
    const float* tokens = (const float*)d_in[0];
    const float* W      = (const float*)d_in[1];
    float* out = (float*)d_out;
    float* ws  = (float*)d_ws;

    auto need = [](int ks) -> size_t {
        return ((size_t)ks * T_TOKENS * NEXP + 2u * 256u * 64u) * sizeof(float);
    };

    int ksplit = 0;
    if      (ws_size >= need(4)) ksplit = 4;
    else if (ws_size >= need(2)) ksplit = 2;
    else if (ws_size >= need(1)) ksplit = 1;

    if (ksplit > 0) {
        float* partial = ws;
        float* wsP = ws + (size_t)ksplit * T_TOKENS * NEXP;
        float* wsC = wsP + 256 * 64;
        const int klen = HIDDEN / ksplit;
        gemm_kernel<<<NTB * ksplit, 512, 0, stream>>>(tokens, W, partial, ksplit, klen);
        epilogue_kernel<<<256, 256, 0, stream>>>(partial, out, wsP, wsC, ksplit);
        aux_kernel<<<1, 256, 0, stream>>>(wsP, wsC, out, 256);
    } else if (ws_size >= (size_t)NTB * 64 * 2 * sizeof(float)) {
        float* wsP = ws;
        float* wsC = ws + (size_t)NTB * 64;
        router_fused<<<NTB, 512, 0, stream>>>(tokens, W, out, wsP, wsC, 0);
        aux_kernel<<<1, 256, 0, stream>>>(wsP, wsC, out, NTB);
    } else {
        hipMemsetAsync(d_ws, 0, 128 * sizeof(float), stream);
        float* wsP = ws;
        float* wsC = ws + 64;
        router_fused<<<NTB, 512, 0, stream>>>(tokens, W, out, wsP, wsC, 1);
        aux_kernel<<<1, 256, 0, stream>>>(wsP, wsC, out, 1);
    }
}